// Round 19
// baseline (164.170 us; speedup 1.0000x reference)
//
#include <hip/hip_runtime.h>

// NPairDiscriminator: N=8192, D=128, tau=0.5. f32 inputs, f32 scalar output.
// loss = mean_i 0.5*(log d1_i + log d2_i - 4*(n1_i . n2_i))
//   d1_i = T[i] - e^2,  d2_i = T[NR+i] - e^2   (|n|^2 == 1 after normalize)
// T[q] = sum over ALL 16384 rows of exp((n_q . n_j)/tau). Gram is SYMMETRIC:
// diag + above-diagonal blocks only (56% work); above-tiles feed row AND col
// sums. R19: 32-key tiles -> 18 KB LDS/block -> 8 blocks/CU (residency was the
// binding constraint: time ~ const/(waves/SIMD) across R4..R18).

#define NR 8192
#define DIM 128
#define SCALE_EXP2 2.885390081777927f   // 1/(tau*ln2)
#define LOG2E 1.442695040888963f
#define LN2 0.6931471805599453f
#define E2 7.38905609893065f             // exp(1/tau) = e^2, the diag term
#define NTL 16                           // 32-key tiles per 512-key quarter-slice

typedef __attribute__((ext_vector_type(8))) short short8;    // 8 bf16 (MFMA A/B frag)
typedef __attribute__((ext_vector_type(4))) float f32x4;
typedef __attribute__((ext_vector_type(16))) float f32x16;   // 32x32 MFMA C/D frag

__device__ unsigned short gN[2 * NR * DIM];   // [n1; n2] normalized bf16 (keys)
__device__ unsigned short gNs[2 * NR * DIM];  // gN * SCALE_EXP2 bf16 (queries)
__device__ float gT[2 * NR];                  // row sums

__device__ inline float b2f(unsigned short h) {
    union { unsigned int u; float f; } x; x.u = ((unsigned int)h) << 16; return x.f;
}
__device__ inline unsigned short f2b(float f) {   // native cast -> v_cvt bf16 (RNE)
    __bf16 h = (__bf16)f;
    unsigned short s;
    __builtin_memcpy(&s, &h, 2);
    return s;
}
__device__ inline short8 ldf8(const float* __restrict__ p) {   // 8 f32 -> bf16 frag
    f32x4 a = *(const f32x4*)p;
    f32x4 b = *(const f32x4*)(p + 4);
    short8 r;
#pragma unroll
    for (int j = 0; j < 4; ++j) r[j] = (short)f2b(a[j]);
#pragma unroll
    for (int j = 0; j < 4; ++j) r[4 + j] = (short)f2b(b[j]);
    return r;
}
__device__ inline f32x16 zero16() {
    f32x16 z;
#pragma unroll
    for (int i = 0; i < 16; ++i) z[i] = 0.0f;
    return z;
}
__device__ inline void gload_lds16(const void* g, void* l) {   // 16B async global->LDS
    __builtin_amdgcn_global_load_lds(
        (const __attribute__((address_space(1))) unsigned int*)g,
        (__attribute__((address_space(3))) unsigned int*)l, 16, 0, 0);
}

// ---------- fused projection: n = normalize(fc2(elu(fc1(z)))); zeroes gT, d_out ----------
// grid (128, 2), block 128 = 2 waves x 32 rows.
__global__ __launch_bounds__(128) void k_proj(
        const float* __restrict__ Z1, const float* __restrict__ Z2,
        const float* __restrict__ W1, const float* __restrict__ B1,
        const float* __restrict__ W2, const float* __restrict__ B2,
        float* __restrict__ out) {
    __shared__ unsigned short hfrag[2][8][64][8];   // [wave][kc][lane][j], 16 KB
    int t = threadIdx.x, w = t >> 6, l = t & 63;
    int lr = l & 31, lh = l >> 5;
    const float* Z = blockIdx.y ? Z2 : Z1;
    long rbase = (long)blockIdx.x * 64 + w * 32;

    int gi = ((int)blockIdx.y * 128 + (int)blockIdx.x) * 128 + t;
    if (gi < 2 * NR) gT[gi] = 0.0f;
    if (gi == 0) out[0] = 0.0f;

    short8 zf[8];
#pragma unroll
    for (int kc = 0; kc < 8; ++kc)
        zf[kc] = ldf8(Z + (rbase + lr) * DIM + kc * 16 + lh * 8);

    // layer 1 + elu, scatter to LDS in A-fragment layout (wave-private slice)
#pragma unroll
    for (int tt = 0; tt < 4; ++tt) {
        short8 wf[8];
#pragma unroll
        for (int kc = 0; kc < 8; ++kc)
            wf[kc] = ldf8(W1 + (tt * 32 + lr) * DIM + kc * 16 + lh * 8);
        f32x16 a = zero16();
#pragma unroll
        for (int kc = 0; kc < 8; ++kc)
            a = __builtin_amdgcn_mfma_f32_32x32x16_bf16(zf[kc], wf[kc], a, 0, 0, 0);
        float bias = B1[tt * 32 + lr];
        int col = tt * 32 + lr;
#pragma unroll
        for (int r = 0; r < 16; ++r) {
            float v = a[r] + bias;
            if (v <= 0.0f) v = __builtin_amdgcn_exp2f(v * LOG2E) - 1.0f;   // elu
            int ro = (r & 3) + 8 * (r >> 2) + 4 * lh;
            hfrag[w][col >> 4][ro | (((col >> 3) & 1) << 5)][col & 7] = f2b(v);
        }
    }
    __syncthreads();

    short8 af[8];
#pragma unroll
    for (int kc = 0; kc < 8; ++kc)
        af[kc] = *(const short8*)&hfrag[w][kc][l][0];

    f32x16 acc[4];
#pragma unroll
    for (int tt = 0; tt < 4; ++tt) {
        short8 wf[8];
#pragma unroll
        for (int kc = 0; kc < 8; ++kc)
            wf[kc] = ldf8(W2 + (tt * 32 + lr) * DIM + kc * 16 + lh * 8);
        f32x16 a = zero16();
#pragma unroll
        for (int kc = 0; kc < 8; ++kc)
            a = __builtin_amdgcn_mfma_f32_32x32x16_bf16(af[kc], wf[kc], a, 0, 0, 0);
        float bias = B2[tt * 32 + lr];
#pragma unroll
        for (int r = 0; r < 16; ++r) a[r] += bias;
        acc[tt] = a;
    }
    float ss[16];
#pragma unroll
    for (int r = 0; r < 16; ++r)
        ss[r] = acc[0][r] * acc[0][r] + acc[1][r] * acc[1][r]
              + acc[2][r] * acc[2][r] + acc[3][r] * acc[3][r];
#pragma unroll
    for (int r = 0; r < 16; ++r) {
        ss[r] += __shfl_xor(ss[r], 1);  ss[r] += __shfl_xor(ss[r], 2);
        ss[r] += __shfl_xor(ss[r], 4);  ss[r] += __shfl_xor(ss[r], 8);
        ss[r] += __shfl_xor(ss[r], 16);
    }
    long nbase = (long)blockIdx.y * NR + rbase;
#pragma unroll
    for (int r = 0; r < 16; ++r) {
        float inv = 1.0f / fmaxf(sqrtf(ss[r]), 1e-12f);
        long row = nbase + (r & 3) + 8 * (r >> 2) + 4 * lh;
#pragma unroll
        for (int tt = 0; tt < 4; ++tt) {
            float v = acc[tt][r] * inv;
            gN[row * DIM + tt * 32 + lr]  = f2b(v);
            gNs[row * DIM + tt * 32 + lr] = f2b(v * SCALE_EXP2);
        }
    }
}

// ---------- symmetric fused exp-sim, quarter-slice blocks, 18 KB LDS ----------
// 576 jobs (128 diag + 448 above) x 4 quarter-slices = 2304 blocks x 4 waves.
// 18 KB/block -> 8 blocks/CU (thread-capped) = ~8 waves/SIMD resident.
// Job: panel p (128 q-rows), slice s; group(p)=p>>4; block covers keys
// [s*2048 + quarter*512, +512) as 16 tiles of 32 keys (8 KB, double-buffered).
// Diag (s==group): row sums only. Above: row sums AND col sums via colacc.
__global__ __launch_bounds__(256, 6) void k_sim() {
    __shared__ char smem[2 * 8192];      // double-buffered 32-key tiles
    __shared__ float colacc[512];        // per-block column accumulator (2 KB)
    int b = blockIdx.x;
    int job = b >> 2, quarter = b & 3;
    int p, s, diag;
    if (job < 128) { p = job; s = job >> 4; diag = 1; }
    else {
        int r = job - 128, g = 0;
        for (;;) { int sz = 16 * (7 - g); if (r < sz) break; r -= sz; ++g; }
        int within = 7 - g;
        p = (g << 4) + r / within;
        s = g + 1 + r % within;
        diag = 0;
    }
    int t = threadIdx.x, w = t >> 6, l = t & 63;
    int lr = l & 31, lh = l >> 5;
    long qbase = (long)p * 128 + w * 32;
    long kb = (long)s * 2048 + (long)quarter * 512;

    if (!diag)
        for (int i = t; i < 512; i += 256) colacc[i] = 0.0f;   // first barrier orders this

    short8 qf[8];
#pragma unroll
    for (int kc = 0; kc < 8; ++kc)
        qf[kc] = *(const short8*)(gNs + (qbase + lr) * DIM + kc * 16 + lh * 8);
    float rs[16];
#pragma unroll
    for (int r = 0; r < 16; ++r) rs[r] = 0.0f;

    // stage 32x128 bf16 tile (8 KB = 512 16B-chunks) with 256 threads: 2/thread.
    // linear LDS dest, inverse-swizzled global src: j = (i&~15)|((i&15)^((i>>4)&7));
    // read side applies the same involution. gload dest is wave-uniform base.
#define STAGE(BUF, TILE) do {                                                        \
    const unsigned short* _tb = gN + (kb + (long)(TILE) * 32) * DIM;                 \
    _Pragma("unroll")                                                                \
    for (int _c = 0; _c < 2; ++_c) {                                                 \
        int _i = _c * 256 + t;                                                       \
        int _j = (_i & ~15) | ((_i & 15) ^ ((_i >> 4) & 7));                         \
        gload_lds16(_tb + _j * 8, smem + (BUF) * 8192 + _c * 4096 + w * 1024);       \
    }                                                                                \
} while (0)

    STAGE(0, 0);
    for (int tt = 0; tt < NTL; ++tt) {
        int cur = tt & 1;
        if (tt + 1 < NTL) {
            STAGE(cur ^ 1, tt + 1);
            asm volatile("s_waitcnt vmcnt(2)" ::: "memory");   // tile tt arrived
        } else {
            asm volatile("s_waitcnt vmcnt(0)" ::: "memory");
        }
        __builtin_amdgcn_s_barrier();
        const char* bufp = smem + cur * 8192;

        short8 bf[8];
#pragma unroll
        for (int kc = 0; kc < 8; ++kc) {
            int chunk = ((kc << 1) | lh) ^ (lr & 7);
            bf[kc] = *(const short8*)(bufp + lr * 256 + chunk * 16);
        }
        f32x16 c = zero16();
#pragma unroll
        for (int kc = 0; kc < 8; ++kc)
            c = __builtin_amdgcn_mfma_f32_32x32x16_bf16(qf[kc], bf[kc], c, 0, 0, 0);
        float cs = 0.0f;
#pragma unroll
        for (int r = 0; r < 16; ++r) {
            float e = __builtin_amdgcn_exp2f(c[r]);
            rs[r] += e;                     // row accumulation (query dim)
            cs += e;                        // column partial (this lane's 16 rows)
        }
        if (!diag) {
            cs += __shfl_xor(cs, 32);       // col=lane&31 split across lane/lane+32
            if (l < 32)
                atomicAdd(&colacc[tt * 32 + l], cs);   // LDS atomic (lgkmcnt, not vmcnt)
        }
        __builtin_amdgcn_s_barrier();   // all waves done reading before overwrite
    }
#undef STAGE

#pragma unroll
    for (int r = 0; r < 16; ++r) {
        rs[r] += __shfl_xor(rs[r], 1);  rs[r] += __shfl_xor(rs[r], 2);
        rs[r] += __shfl_xor(rs[r], 4);  rs[r] += __shfl_xor(rs[r], 8);
        rs[r] += __shfl_xor(rs[r], 16);
    }
    if (lr == 0) {   // lanes 0 / 32 own 16 rows each
#pragma unroll
        for (int r = 0; r < 16; ++r) {
            int ro = (r & 3) + 8 * (r >> 2) + 4 * lh;
            atomicAdd(&gT[qbase + ro], rs[r]);
        }
    }
    if (!diag) {                          // flush column sums: T[k] += colacc[k]
        __syncthreads();
        for (int i = t; i < 512; i += 256)
            atomicAdd(&gT[kb + i], colacc[i]);
    }
}

// ---------- per-row loss + global mean (diag term == e^2 analytically) ----------
__global__ __launch_bounds__(256) void k_loss(float* __restrict__ out) {
    int t = threadIdx.x, w = t >> 6, l = t & 63;
    int gw = blockIdx.x * 4 + w;
    float lsum = 0.0f;
    for (int row = gw; row < NR; row += 1024) {
        unsigned int pa = *(const unsigned int*)(gN + (long)row * DIM + l * 2);
        unsigned int pb = *(const unsigned int*)(gN + (long)(NR + row) * DIM + l * 2);
        float a0 = b2f((unsigned short)(pa & 0xFFFFu)), a1 = b2f((unsigned short)(pa >> 16));
        float b0 = b2f((unsigned short)(pb & 0xFFFFu)), b1 = b2f((unsigned short)(pb >> 16));
        float cr = a0 * b0 + a1 * b1;
#pragma unroll
        for (int off = 1; off < 64; off <<= 1)
            cr += __shfl_xor(cr, off);
        if (l == 0) {
            float d1 = gT[row]      - E2;
            float d2 = gT[NR + row] - E2;
            lsum += (__builtin_amdgcn_logf(d1) + __builtin_amdgcn_logf(d2)) * LN2 - 4.0f * cr;
        }
    }
    if (l == 0) atomicAdd(out, lsum * (0.5f / 8192.0f));
}

extern "C" void kernel_launch(void* const* d_in, const int* in_sizes, int n_in,
                              void* d_out, int out_size, void* d_ws, size_t ws_size,
                              hipStream_t stream) {
    const float* z1 = (const float*)d_in[0];
    const float* z2 = (const float*)d_in[1];
    const float* w1 = (const float*)d_in[2];
    const float* b1 = (const float*)d_in[3];
    const float* w2 = (const float*)d_in[4];
    const float* b2 = (const float*)d_in[5];

    k_proj<<<dim3(128, 2), 128, 0, stream>>>(z1, z2, w1, b1, w2, b2, (float*)d_out);
    k_sim<<<dim3(2304), 256, 0, stream>>>();
    k_loss<<<dim3(256), 256, 0, stream>>>((float*)d_out);
}

// Round 20
// 127.310 us; speedup vs baseline: 1.2895x; 1.2895x over previous
//
#include <hip/hip_runtime.h>

// NPairDiscriminator: N=8192, D=128, tau=0.5. f32 inputs, f32 scalar output.
// loss = mean_i 0.5*(log d1_i + log d2_i - 4*(n1_i . n2_i))
//   d1_i = T[i] - e^2,  d2_i = T[NR+i] - e^2   (|n|^2 == 1 after normalize)
// T[q] = sum over ALL 16384 rows of exp((n_q . n_j)/tau). Gram is SYMMETRIC:
// diag + above-diagonal blocks only (56% work); above-tiles feed row AND col
// sums. Quarter-slice blocks (18 KB LDS) for residency. launch_bounds MUST be
// (256,4): (256,6) forced an ~85-VGPR budget onto a ~100-VGPR live set ->
// wholesale scratch spill (R19: VGPR 40, FETCH 74 MB, WRITE 68 MB, 2x slower).

#define NR 8192
#define DIM 128
#define SCALE_EXP2 2.885390081777927f   // 1/(tau*ln2)
#define LOG2E 1.442695040888963f
#define LN2 0.6931471805599453f
#define E2 7.38905609893065f             // exp(1/tau) = e^2, the diag term
#define NTL 16                           // 32-key tiles per 512-key quarter-slice

typedef __attribute__((ext_vector_type(8))) short short8;    // 8 bf16 (MFMA A/B frag)
typedef __attribute__((ext_vector_type(4))) float f32x4;
typedef __attribute__((ext_vector_type(16))) float f32x16;   // 32x32 MFMA C/D frag

__device__ unsigned short gN[2 * NR * DIM];   // [n1; n2] normalized bf16 (keys)
__device__ unsigned short gNs[2 * NR * DIM];  // gN * SCALE_EXP2 bf16 (queries)
__device__ float gT[2 * NR];                  // row sums

__device__ inline float b2f(unsigned short h) {
    union { unsigned int u; float f; } x; x.u = ((unsigned int)h) << 16; return x.f;
}
__device__ inline unsigned short f2b(float f) {   // native cast -> v_cvt bf16 (RNE)
    __bf16 h = (__bf16)f;
    unsigned short s;
    __builtin_memcpy(&s, &h, 2);
    return s;
}
__device__ inline short8 ldf8(const float* __restrict__ p) {   // 8 f32 -> bf16 frag
    f32x4 a = *(const f32x4*)p;
    f32x4 b = *(const f32x4*)(p + 4);
    short8 r;
#pragma unroll
    for (int j = 0; j < 4; ++j) r[j] = (short)f2b(a[j]);
#pragma unroll
    for (int j = 0; j < 4; ++j) r[4 + j] = (short)f2b(b[j]);
    return r;
}
__device__ inline f32x16 zero16() {
    f32x16 z;
#pragma unroll
    for (int i = 0; i < 16; ++i) z[i] = 0.0f;
    return z;
}
__device__ inline void gload_lds16(const void* g, void* l) {   // 16B async global->LDS
    __builtin_amdgcn_global_load_lds(
        (const __attribute__((address_space(1))) unsigned int*)g,
        (__attribute__((address_space(3))) unsigned int*)l, 16, 0, 0);
}

// ---------- fused projection: n = normalize(fc2(elu(fc1(z)))); zeroes gT, d_out ----------
// grid (128, 2), block 128 = 2 waves x 32 rows.
__global__ __launch_bounds__(128) void k_proj(
        const float* __restrict__ Z1, const float* __restrict__ Z2,
        const float* __restrict__ W1, const float* __restrict__ B1,
        const float* __restrict__ W2, const float* __restrict__ B2,
        float* __restrict__ out) {
    __shared__ unsigned short hfrag[2][8][64][8];   // [wave][kc][lane][j], 16 KB
    int t = threadIdx.x, w = t >> 6, l = t & 63;
    int lr = l & 31, lh = l >> 5;
    const float* Z = blockIdx.y ? Z2 : Z1;
    long rbase = (long)blockIdx.x * 64 + w * 32;

    int gi = ((int)blockIdx.y * 128 + (int)blockIdx.x) * 128 + t;
    if (gi < 2 * NR) gT[gi] = 0.0f;
    if (gi == 0) out[0] = 0.0f;

    short8 zf[8];
#pragma unroll
    for (int kc = 0; kc < 8; ++kc)
        zf[kc] = ldf8(Z + (rbase + lr) * DIM + kc * 16 + lh * 8);

    // layer 1 + elu, scatter to LDS in A-fragment layout (wave-private slice)
#pragma unroll
    for (int tt = 0; tt < 4; ++tt) {
        short8 wf[8];
#pragma unroll
        for (int kc = 0; kc < 8; ++kc)
            wf[kc] = ldf8(W1 + (tt * 32 + lr) * DIM + kc * 16 + lh * 8);
        f32x16 a = zero16();
#pragma unroll
        for (int kc = 0; kc < 8; ++kc)
            a = __builtin_amdgcn_mfma_f32_32x32x16_bf16(zf[kc], wf[kc], a, 0, 0, 0);
        float bias = B1[tt * 32 + lr];
        int col = tt * 32 + lr;
#pragma unroll
        for (int r = 0; r < 16; ++r) {
            float v = a[r] + bias;
            if (v <= 0.0f) v = __builtin_amdgcn_exp2f(v * LOG2E) - 1.0f;   // elu
            int ro = (r & 3) + 8 * (r >> 2) + 4 * lh;
            hfrag[w][col >> 4][ro | (((col >> 3) & 1) << 5)][col & 7] = f2b(v);
        }
    }
    __syncthreads();

    short8 af[8];
#pragma unroll
    for (int kc = 0; kc < 8; ++kc)
        af[kc] = *(const short8*)&hfrag[w][kc][l][0];

    f32x16 acc[4];
#pragma unroll
    for (int tt = 0; tt < 4; ++tt) {
        short8 wf[8];
#pragma unroll
        for (int kc = 0; kc < 8; ++kc)
            wf[kc] = ldf8(W2 + (tt * 32 + lr) * DIM + kc * 16 + lh * 8);
        f32x16 a = zero16();
#pragma unroll
        for (int kc = 0; kc < 8; ++kc)
            a = __builtin_amdgcn_mfma_f32_32x32x16_bf16(af[kc], wf[kc], a, 0, 0, 0);
        float bias = B2[tt * 32 + lr];
#pragma unroll
        for (int r = 0; r < 16; ++r) a[r] += bias;
        acc[tt] = a;
    }
    float ss[16];
#pragma unroll
    for (int r = 0; r < 16; ++r)
        ss[r] = acc[0][r] * acc[0][r] + acc[1][r] * acc[1][r]
              + acc[2][r] * acc[2][r] + acc[3][r] * acc[3][r];
#pragma unroll
    for (int r = 0; r < 16; ++r) {
        ss[r] += __shfl_xor(ss[r], 1);  ss[r] += __shfl_xor(ss[r], 2);
        ss[r] += __shfl_xor(ss[r], 4);  ss[r] += __shfl_xor(ss[r], 8);
        ss[r] += __shfl_xor(ss[r], 16);
    }
    long nbase = (long)blockIdx.y * NR + rbase;
#pragma unroll
    for (int r = 0; r < 16; ++r) {
        float inv = 1.0f / fmaxf(sqrtf(ss[r]), 1e-12f);
        long row = nbase + (r & 3) + 8 * (r >> 2) + 4 * lh;
#pragma unroll
        for (int tt = 0; tt < 4; ++tt) {
            float v = acc[tt][r] * inv;
            gN[row * DIM + tt * 32 + lr]  = f2b(v);
            gNs[row * DIM + tt * 32 + lr] = f2b(v * SCALE_EXP2);
        }
    }
}

// ---------- symmetric fused exp-sim, quarter-slice blocks, 18 KB LDS ----------
// 576 jobs (128 diag + 448 above) x 4 quarter-slices = 2304 blocks x 4 waves.
// ~9 blocks/CU offered; resident capped by VGPR (~100 -> ~5 waves/SIMD).
// Job: panel p (128 q-rows), slice s; group(p)=p>>4; block covers keys
// [s*2048 + quarter*512, +512) as 16 tiles of 32 keys (8 KB, double-buffered).
// Diag (s==group): row sums only. Above: row sums AND col sums via colacc.
__global__ __launch_bounds__(256, 4) void k_sim() {
    __shared__ char smem[2 * 8192];      // double-buffered 32-key tiles
    __shared__ float colacc[512];        // per-block column accumulator (2 KB)
    int b = blockIdx.x;
    int job = b >> 2, quarter = b & 3;
    int p, s, diag;
    if (job < 128) { p = job; s = job >> 4; diag = 1; }
    else {
        int r = job - 128, g = 0;
        for (;;) { int sz = 16 * (7 - g); if (r < sz) break; r -= sz; ++g; }
        int within = 7 - g;
        p = (g << 4) + r / within;
        s = g + 1 + r % within;
        diag = 0;
    }
    int t = threadIdx.x, w = t >> 6, l = t & 63;
    int lr = l & 31, lh = l >> 5;
    long qbase = (long)p * 128 + w * 32;
    long kb = (long)s * 2048 + (long)quarter * 512;

    if (!diag)
        for (int i = t; i < 512; i += 256) colacc[i] = 0.0f;   // first barrier orders this

    short8 qf[8];
#pragma unroll
    for (int kc = 0; kc < 8; ++kc)
        qf[kc] = *(const short8*)(gNs + (qbase + lr) * DIM + kc * 16 + lh * 8);
    float rs[16];
#pragma unroll
    for (int r = 0; r < 16; ++r) rs[r] = 0.0f;

    // stage 32x128 bf16 tile (8 KB = 512 16B-chunks) with 256 threads: 2/thread.
    // linear LDS dest, inverse-swizzled global src: j = (i&~15)|((i&15)^((i>>4)&7));
    // read side applies the same involution. gload dest is wave-uniform base.
#define STAGE(BUF, TILE) do {                                                        \
    const unsigned short* _tb = gN + (kb + (long)(TILE) * 32) * DIM;                 \
    _Pragma("unroll")                                                                \
    for (int _c = 0; _c < 2; ++_c) {                                                 \
        int _i = _c * 256 + t;                                                       \
        int _j = (_i & ~15) | ((_i & 15) ^ ((_i >> 4) & 7));                         \
        gload_lds16(_tb + _j * 8, smem + (BUF) * 8192 + _c * 4096 + w * 1024);       \
    }                                                                                \
} while (0)

    STAGE(0, 0);
    for (int tt = 0; tt < NTL; ++tt) {
        int cur = tt & 1;
        if (tt + 1 < NTL) {
            STAGE(cur ^ 1, tt + 1);
            asm volatile("s_waitcnt vmcnt(2)" ::: "memory");   // tile tt arrived
        } else {
            asm volatile("s_waitcnt vmcnt(0)" ::: "memory");
        }
        __builtin_amdgcn_s_barrier();
        const char* bufp = smem + cur * 8192;

        short8 bf[8];
#pragma unroll
        for (int kc = 0; kc < 8; ++kc) {
            int chunk = ((kc << 1) | lh) ^ (lr & 7);
            bf[kc] = *(const short8*)(bufp + lr * 256 + chunk * 16);
        }
        f32x16 c = zero16();
#pragma unroll
        for (int kc = 0; kc < 8; ++kc)
            c = __builtin_amdgcn_mfma_f32_32x32x16_bf16(qf[kc], bf[kc], c, 0, 0, 0);
        float cs = 0.0f;
#pragma unroll
        for (int r = 0; r < 16; ++r) {
            float e = __builtin_amdgcn_exp2f(c[r]);
            rs[r] += e;                     // row accumulation (query dim)
            cs += e;                        // column partial (this lane's 16 rows)
        }
        if (!diag) {
            cs += __shfl_xor(cs, 32);       // col=lane&31 split across lane/lane+32
            if (l < 32)
                atomicAdd(&colacc[tt * 32 + l], cs);   // LDS atomic (lgkmcnt, not vmcnt)
        }
        __builtin_amdgcn_s_barrier();   // all waves done reading before overwrite
    }
#undef STAGE

#pragma unroll
    for (int r = 0; r < 16; ++r) {
        rs[r] += __shfl_xor(rs[r], 1);  rs[r] += __shfl_xor(rs[r], 2);
        rs[r] += __shfl_xor(rs[r], 4);  rs[r] += __shfl_xor(rs[r], 8);
        rs[r] += __shfl_xor(rs[r], 16);
    }
    if (lr == 0) {   // lanes 0 / 32 own 16 rows each
#pragma unroll
        for (int r = 0; r < 16; ++r) {
            int ro = (r & 3) + 8 * (r >> 2) + 4 * lh;
            atomicAdd(&gT[qbase + ro], rs[r]);
        }
    }
    if (!diag) {                          // flush column sums: T[k] += colacc[k]
        __syncthreads();
        for (int i = t; i < 512; i += 256)
            atomicAdd(&gT[kb + i], colacc[i]);
    }
}

// ---------- per-row loss + global mean (diag term == e^2 analytically) ----------
__global__ __launch_bounds__(256) void k_loss(float* __restrict__ out) {
    int t = threadIdx.x, w = t >> 6, l = t & 63;
    int gw = blockIdx.x * 4 + w;
    float lsum = 0.0f;
    for (int row = gw; row < NR; row += 1024) {
        unsigned int pa = *(const unsigned int*)(gN + (long)row * DIM + l * 2);
        unsigned int pb = *(const unsigned int*)(gN + (long)(NR + row) * DIM + l * 2);
        float a0 = b2f((unsigned short)(pa & 0xFFFFu)), a1 = b2f((unsigned short)(pa >> 16));
        float b0 = b2f((unsigned short)(pb & 0xFFFFu)), b1 = b2f((unsigned short)(pb >> 16));
        float cr = a0 * b0 + a1 * b1;
#pragma unroll
        for (int off = 1; off < 64; off <<= 1)
            cr += __shfl_xor(cr, off);
        if (l == 0) {
            float d1 = gT[row]      - E2;
            float d2 = gT[NR + row] - E2;
            lsum += (__builtin_amdgcn_logf(d1) + __builtin_amdgcn_logf(d2)) * LN2 - 4.0f * cr;
        }
    }
    if (l == 0) atomicAdd(out, lsum * (0.5f / 8192.0f));
}

extern "C" void kernel_launch(void* const* d_in, const int* in_sizes, int n_in,
                              void* d_out, int out_size, void* d_ws, size_t ws_size,
                              hipStream_t stream) {
    const float* z1 = (const float*)d_in[0];
    const float* z2 = (const float*)d_in[1];
    const float* w1 = (const float*)d_in[2];
    const float* b1 = (const float*)d_in[3];
    const float* w2 = (const float*)d_in[4];
    const float* b2 = (const float*)d_in[5];

    k_proj<<<dim3(128, 2), 128, 0, stream>>>(z1, z2, w1, b1, w2, b2, (float*)d_out);
    k_sim<<<dim3(2304), 256, 0, stream>>>();
    k_loss<<<dim3(256), 256, 0, stream>>>((float*)d_out);
}

// Round 21
// 111.118 us; speedup vs baseline: 1.4774x; 1.1457x over previous
//
#include <hip/hip_runtime.h>

// NPairDiscriminator: N=8192, D=128, tau=0.5. f32 inputs, f32 scalar output.
// loss = mean_i 0.5*(log d1_i + log d2_i - 4*(n1_i . n2_i))
//   d1_i = T[i] - e^2,  d2_i = T[NR+i] - e^2   (|n|^2 == 1 after normalize)
// T[q] = sum over ALL 16384 rows of exp((n_q . n_j)/tau). Gram is SYMMETRIC:
// diag + above-diagonal blocks only (56% work), each above-tile's exps feed
// row sums AND col sums. Half-slice blocks (R18 best: 111.5 us total).
// CONVERGED STRUCTURE — R4..R20 variants (occupancy, ILP, LDS economy,
// barrier count, buffer depth, setprio, deferred exp, tile geometry) all
// land in [76,93] us for k_sim; the 2-phase stage/barrier schedule's fixed
// overhead is the attractor (m233). Quarter-slices (R20) and (256,6) (R19)
// both regress — do not revisit.

#define NR 8192
#define DIM 128
#define SCALE_EXP2 2.885390081777927f   // 1/(tau*ln2)
#define LOG2E 1.442695040888963f
#define LN2 0.6931471805599453f
#define E2 7.38905609893065f             // exp(1/tau) = e^2, the diag term
#define NTL 16                           // 64-key tiles per 1024-key half-slice

typedef __attribute__((ext_vector_type(8))) short short8;    // 8 bf16 (MFMA A/B frag)
typedef __attribute__((ext_vector_type(4))) float f32x4;
typedef __attribute__((ext_vector_type(16))) float f32x16;   // 32x32 MFMA C/D frag

__device__ unsigned short gN[2 * NR * DIM];   // [n1; n2] normalized bf16 (keys)
__device__ unsigned short gNs[2 * NR * DIM];  // gN * SCALE_EXP2 bf16 (queries)
__device__ float gT[2 * NR];                  // row sums

__device__ inline float b2f(unsigned short h) {
    union { unsigned int u; float f; } x; x.u = ((unsigned int)h) << 16; return x.f;
}
__device__ inline unsigned short f2b(float f) {   // native cast -> v_cvt bf16 (RNE)
    __bf16 h = (__bf16)f;
    unsigned short s;
    __builtin_memcpy(&s, &h, 2);
    return s;
}
__device__ inline short8 ldf8(const float* __restrict__ p) {   // 8 f32 -> bf16 frag
    f32x4 a = *(const f32x4*)p;
    f32x4 b = *(const f32x4*)(p + 4);
    short8 r;
#pragma unroll
    for (int j = 0; j < 4; ++j) r[j] = (short)f2b(a[j]);
#pragma unroll
    for (int j = 0; j < 4; ++j) r[4 + j] = (short)f2b(b[j]);
    return r;
}
__device__ inline f32x16 zero16() {
    f32x16 z;
#pragma unroll
    for (int i = 0; i < 16; ++i) z[i] = 0.0f;
    return z;
}
__device__ inline void gload_lds16(const void* g, void* l) {   // 16B async global->LDS
    __builtin_amdgcn_global_load_lds(
        (const __attribute__((address_space(1))) unsigned int*)g,
        (__attribute__((address_space(3))) unsigned int*)l, 16, 0, 0);
}

// ---------- fused projection: n = normalize(fc2(elu(fc1(z)))); zeroes gT, d_out ----------
// grid (128, 2), block 128 = 2 waves x 32 rows.
__global__ __launch_bounds__(128) void k_proj(
        const float* __restrict__ Z1, const float* __restrict__ Z2,
        const float* __restrict__ W1, const float* __restrict__ B1,
        const float* __restrict__ W2, const float* __restrict__ B2,
        float* __restrict__ out) {
    __shared__ unsigned short hfrag[2][8][64][8];   // [wave][kc][lane][j], 16 KB
    int t = threadIdx.x, w = t >> 6, l = t & 63;
    int lr = l & 31, lh = l >> 5;
    const float* Z = blockIdx.y ? Z2 : Z1;
    long rbase = (long)blockIdx.x * 64 + w * 32;

    int gi = ((int)blockIdx.y * 128 + (int)blockIdx.x) * 128 + t;
    if (gi < 2 * NR) gT[gi] = 0.0f;
    if (gi == 0) out[0] = 0.0f;

    short8 zf[8];
#pragma unroll
    for (int kc = 0; kc < 8; ++kc)
        zf[kc] = ldf8(Z + (rbase + lr) * DIM + kc * 16 + lh * 8);

    // layer 1 + elu, scatter to LDS in A-fragment layout (wave-private slice)
#pragma unroll
    for (int tt = 0; tt < 4; ++tt) {
        short8 wf[8];
#pragma unroll
        for (int kc = 0; kc < 8; ++kc)
            wf[kc] = ldf8(W1 + (tt * 32 + lr) * DIM + kc * 16 + lh * 8);
        f32x16 a = zero16();
#pragma unroll
        for (int kc = 0; kc < 8; ++kc)
            a = __builtin_amdgcn_mfma_f32_32x32x16_bf16(zf[kc], wf[kc], a, 0, 0, 0);
        float bias = B1[tt * 32 + lr];
        int col = tt * 32 + lr;
#pragma unroll
        for (int r = 0; r < 16; ++r) {
            float v = a[r] + bias;
            if (v <= 0.0f) v = __builtin_amdgcn_exp2f(v * LOG2E) - 1.0f;   // elu
            int ro = (r & 3) + 8 * (r >> 2) + 4 * lh;
            hfrag[w][col >> 4][ro | (((col >> 3) & 1) << 5)][col & 7] = f2b(v);
        }
    }
    __syncthreads();

    short8 af[8];
#pragma unroll
    for (int kc = 0; kc < 8; ++kc)
        af[kc] = *(const short8*)&hfrag[w][kc][l][0];

    f32x16 acc[4];
#pragma unroll
    for (int tt = 0; tt < 4; ++tt) {
        short8 wf[8];
#pragma unroll
        for (int kc = 0; kc < 8; ++kc)
            wf[kc] = ldf8(W2 + (tt * 32 + lr) * DIM + kc * 16 + lh * 8);
        f32x16 a = zero16();
#pragma unroll
        for (int kc = 0; kc < 8; ++kc)
            a = __builtin_amdgcn_mfma_f32_32x32x16_bf16(af[kc], wf[kc], a, 0, 0, 0);
        float bias = B2[tt * 32 + lr];
#pragma unroll
        for (int r = 0; r < 16; ++r) a[r] += bias;
        acc[tt] = a;
    }
    float ss[16];
#pragma unroll
    for (int r = 0; r < 16; ++r)
        ss[r] = acc[0][r] * acc[0][r] + acc[1][r] * acc[1][r]
              + acc[2][r] * acc[2][r] + acc[3][r] * acc[3][r];
#pragma unroll
    for (int r = 0; r < 16; ++r) {
        ss[r] += __shfl_xor(ss[r], 1);  ss[r] += __shfl_xor(ss[r], 2);
        ss[r] += __shfl_xor(ss[r], 4);  ss[r] += __shfl_xor(ss[r], 8);
        ss[r] += __shfl_xor(ss[r], 16);
    }
    long nbase = (long)blockIdx.y * NR + rbase;
#pragma unroll
    for (int r = 0; r < 16; ++r) {
        float inv = 1.0f / fmaxf(sqrtf(ss[r]), 1e-12f);
        long row = nbase + (r & 3) + 8 * (r >> 2) + 4 * lh;
#pragma unroll
        for (int tt = 0; tt < 4; ++tt) {
            float v = acc[tt][r] * inv;
            gN[row * DIM + tt * 32 + lr]  = f2b(v);
            gNs[row * DIM + tt * 32 + lr] = f2b(v * SCALE_EXP2);
        }
    }
}

// ---------- symmetric fused exp-sim, half-slice blocks ----------
// 576 jobs (128 diag + 448 above) x 2 half-slices = 1152 blocks x 4 waves
// = 4.5 waves/SIMD. Job: panel p (128 q-rows), slice s; group(p)=p>>4; this
// block covers keys [s*2048 + half*1024, +1024), NTL=16 tiles of 64 keys.
// Diag jobs (s==group): row sums only (within-group transposes covered since
// every panel of the group row-sums the whole slice). Above jobs (s>group):
// row sums to T[q] AND column sums via LDS colacc -> flushed to T[k].
__global__ __launch_bounds__(256, 4) void k_sim() {
    __shared__ char smem[2 * 16384];     // double-buffered 64-key tiles
    __shared__ float colacc[1024];       // per-block column accumulator (4 KB)
    int b = blockIdx.x;
    int job = b >> 1, half = b & 1;
    int p, s, diag;
    if (job < 128) { p = job; s = job >> 4; diag = 1; }
    else {
        int r = job - 128, g = 0;
        for (;;) { int sz = 16 * (7 - g); if (r < sz) break; r -= sz; ++g; }
        int within = 7 - g;
        p = (g << 4) + r / within;
        s = g + 1 + r % within;
        diag = 0;
    }
    int t = threadIdx.x, w = t >> 6, l = t & 63;
    int lr = l & 31, lh = l >> 5;
    long qbase = (long)p * 128 + w * 32;
    long kb = (long)s * 2048 + (long)half * 1024;

    if (!diag)
        for (int i = t; i < 1024; i += 256) colacc[i] = 0.0f;   // first barrier orders this

    short8 qf[8];
#pragma unroll
    for (int kc = 0; kc < 8; ++kc)
        qf[kc] = *(const short8*)(gNs + (qbase + lr) * DIM + kc * 16 + lh * 8);
    float rs[16];
#pragma unroll
    for (int r = 0; r < 16; ++r) rs[r] = 0.0f;

    // stage 64x128 bf16 tile (16 KB) with 256 threads: 4 chunks/thread.
    // linear LDS dest, inverse-swizzled global src: j = (i&~15)|((i&15)^((i>>4)&7));
    // read side applies the same involution.
#define STAGE(BUF, TILE) do {                                                        \
    const unsigned short* _tb = gN + (kb + (long)(TILE) * 64) * DIM;                 \
    _Pragma("unroll")                                                                \
    for (int _c = 0; _c < 4; ++_c) {                                                 \
        int _i = _c * 256 + t;                                                       \
        int _j = (_i & ~15) | ((_i & 15) ^ ((_i >> 4) & 7));                         \
        gload_lds16(_tb + _j * 8, smem + (BUF) * 16384 + (_c * 4 + w) * 1024);       \
    }                                                                                \
} while (0)

    STAGE(0, 0);
    for (int tt = 0; tt < NTL; ++tt) {
        int cur = tt & 1;
        if (tt + 1 < NTL) {
            STAGE(cur ^ 1, tt + 1);
            asm volatile("s_waitcnt vmcnt(4)" ::: "memory");   // tile tt arrived
        } else {
            asm volatile("s_waitcnt vmcnt(0)" ::: "memory");
        }
        __builtin_amdgcn_s_barrier();
        const char* bufp = smem + cur * 16384;
#pragma unroll
        for (int ks = 0; ks < 2; ++ks) {
            short8 bf[8];
#pragma unroll
            for (int kc = 0; kc < 8; ++kc) {
                int chunk = ((kc << 1) | lh) ^ (lr & 7);
                bf[kc] = *(const short8*)(bufp + (ks * 32 + lr) * 256 + chunk * 16);
            }
            f32x16 c = zero16();
#pragma unroll
            for (int kc = 0; kc < 8; ++kc)
                c = __builtin_amdgcn_mfma_f32_32x32x16_bf16(qf[kc], bf[kc], c, 0, 0, 0);
            float cs = 0.0f;
#pragma unroll
            for (int r = 0; r < 16; ++r) {
                float e = __builtin_amdgcn_exp2f(c[r]);
                rs[r] += e;                     // row accumulation (query dim)
                cs += e;                        // column partial (this lane's 16 rows)
            }
            if (!diag) {
                cs += __shfl_xor(cs, 32);       // col=lane&31 split across lane/lane+32
                if (l < 32)
                    atomicAdd(&colacc[tt * 64 + ks * 32 + l], cs);   // LDS atomic
            }
        }
        __builtin_amdgcn_s_barrier();   // all waves done reading before overwrite
    }
#undef STAGE

#pragma unroll
    for (int r = 0; r < 16; ++r) {
        rs[r] += __shfl_xor(rs[r], 1);  rs[r] += __shfl_xor(rs[r], 2);
        rs[r] += __shfl_xor(rs[r], 4);  rs[r] += __shfl_xor(rs[r], 8);
        rs[r] += __shfl_xor(rs[r], 16);
    }
    if (lr == 0) {   // lanes 0 / 32 own 16 rows each
#pragma unroll
        for (int r = 0; r < 16; ++r) {
            int ro = (r & 3) + 8 * (r >> 2) + 4 * lh;
            atomicAdd(&gT[qbase + ro], rs[r]);
        }
    }
    if (!diag) {                          // flush column sums: T[k] += colacc[k]
        __syncthreads();
        for (int i = t; i < 1024; i += 256)
            atomicAdd(&gT[kb + i], colacc[i]);
    }
}

// ---------- per-row loss + global mean (diag term == e^2 analytically) ----------
__global__ __launch_bounds__(256) void k_loss(float* __restrict__ out) {
    int t = threadIdx.x, w = t >> 6, l = t & 63;
    int gw = blockIdx.x * 4 + w;
    float lsum = 0.0f;
    for (int row = gw; row < NR; row += 1024) {
        unsigned int pa = *(const unsigned int*)(gN + (long)row * DIM + l * 2);
        unsigned int pb = *(const unsigned int*)(gN + (long)(NR + row) * DIM + l * 2);
        float a0 = b2f((unsigned short)(pa & 0xFFFFu)), a1 = b2f((unsigned short)(pa >> 16));
        float b0 = b2f((unsigned short)(pb & 0xFFFFu)), b1 = b2f((unsigned short)(pb >> 16));
        float cr = a0 * b0 + a1 * b1;
#pragma unroll
        for (int off = 1; off < 64; off <<= 1)
            cr += __shfl_xor(cr, off);
        if (l == 0) {
            float d1 = gT[row]      - E2;
            float d2 = gT[NR + row] - E2;
            lsum += (__builtin_amdgcn_logf(d1) + __builtin_amdgcn_logf(d2)) * LN2 - 4.0f * cr;
        }
    }
    if (l == 0) atomicAdd(out, lsum * (0.5f / 8192.0f));
}

extern "C" void kernel_launch(void* const* d_in, const int* in_sizes, int n_in,
                              void* d_out, int out_size, void* d_ws, size_t ws_size,
                              hipStream_t stream) {
    const float* z1 = (const float*)d_in[0];
    const float* z2 = (const float*)d_in[1];
    const float* w1 = (const float*)d_in[2];
    const float* b1 = (const float*)d_in[3];
    const float* w2 = (const float*)d_in[4];
    const float* b2 = (const float*)d_in[5];

    k_proj<<<dim3(128, 2), 128, 0, stream>>>(z1, z2, w1, b1, w2, b2, (float*)d_out);
    k_sim<<<dim3(1152), 256, 0, stream>>>();
    k_loss<<<dim3(256), 256, 0, stream>>>((float*)d_out);
}